// Round 4
// baseline (378.536 us; speedup 1.0000x reference)
//
#include <hip/hip_runtime.h>
#include <stdint.h>

typedef unsigned int u32;
typedef unsigned short u16;
typedef float  f32x4 __attribute__((ext_vector_type(4)));
typedef u32    u32x4 __attribute__((ext_vector_type(4)));
typedef __bf16 bf16x8 __attribute__((ext_vector_type(8)));

// fp32 -> bf16 RNE
static __device__ __forceinline__ u16 f2bf(float f){
  u32 u = __builtin_bit_cast(u32, f);
  return (u16)((u + 0x7FFFu + ((u >> 16) & 1u)) >> 16);
}

static __device__ __forceinline__ void async16(const void* g, void* l){
  __builtin_amdgcn_global_load_lds((const __attribute__((address_space(1))) u32*)g,
                                   (__attribute__((address_space(3))) u32*)l, 16, 0, 0);
}

static __device__ __forceinline__ float wave_sum(float v){
#pragma unroll
  for (int o = 32; o > 0; o >>= 1) v += __shfl_xor(v, o, 64);
  return v;
}

// ================= mega prep kernel: cvt (grid-stride) + tp (fp32->bf16 T) + tcvt =========
// Block ranges: has_tp ? [0,4096) even=tp odd=cvt, [4096,4224)=tcvt
//             : [0,2048)=cvt, [2048,2176)=tcvt

static __device__ __forceinline__ void prep_cvt(int sub, const float* __restrict__ S,
                                                const float* __restrict__ P,
                                                u16* __restrict__ SN, u16* __restrict__ PN){
  const size_t o0 = ((size_t)sub*256 + threadIdx.x) * 8;   // stride 2048*256*8 = 4194304
#pragma unroll
  for (int j = 0; j < 4; ++j){
    size_t o = o0 + (size_t)j*4194304;
    f32x4 a = *(const f32x4*)(S + o);
    f32x4 b = *(const f32x4*)(S + o + 4);
    u32x4 w;
    w[0] = (u32)f2bf(a[0]) | ((u32)f2bf(a[1]) << 16);
    w[1] = (u32)f2bf(a[2]) | ((u32)f2bf(a[3]) << 16);
    w[2] = (u32)f2bf(b[0]) | ((u32)f2bf(b[1]) << 16);
    w[3] = (u32)f2bf(b[2]) | ((u32)f2bf(b[3]) << 16);
    *(u32x4*)(SN + o) = w;
  }
#pragma unroll
  for (int j = 0; j < 4; ++j){
    size_t o = o0 + (size_t)j*4194304;
    f32x4 a = *(const f32x4*)(P + o);
    f32x4 b = *(const f32x4*)(P + o + 4);
    u32x4 w;
    w[0] = (u32)f2bf(a[0]) | ((u32)f2bf(a[1]) << 16);
    w[1] = (u32)f2bf(a[2]) | ((u32)f2bf(a[3]) << 16);
    w[2] = (u32)f2bf(b[0]) | ((u32)f2bf(b[1]) << 16);
    w[3] = (u32)f2bf(b[2]) | ((u32)f2bf(b[3]) << 16);
    *(u32x4*)(PN + o) = w;
  }
}

// fp32 [32768][512] -> bf16 [512][32768] transpose+convert; 256b x 64d tile.
// LDS u32 st[64 d][32 pb-slots x4], granule swizzle g^(d&7); writes full-u32 2-way (free),
// reads b128 uniform over banks (verified mapping from R2 k_tp).
static __device__ __forceinline__ void prep_tp(int sub, const float* __restrict__ S,
                                               const float* __restrict__ P,
                                               u16* __restrict__ ST, u16* __restrict__ PT,
                                               u32* st){
  const int bx = sub & 127, by = (sub >> 7) & 7, z = sub >> 10;
  const float* __restrict__ src = z ? P : S;
  u16* __restrict__ dst = z ? PT : ST;
  const int r0 = bx * 256;   // b tile
  const int c0 = by * 64;    // d tile
  const int t = threadIdx.x;
  const int tb = t & 127, th = t >> 7;     // b-pair, d-half
  const float* pA = src + (size_t)(r0 + 2*tb)*512 + c0 + th*32;
  float fa[32], fb[32];
#pragma unroll
  for (int c = 0; c < 8; ++c){
    f32x4 va = *(const f32x4*)(pA + 4*c);
    f32x4 vb = *(const f32x4*)(pA + 512 + 4*c);
#pragma unroll
    for (int e = 0; e < 4; ++e){ fa[4*c+e] = va[e]; fb[4*c+e] = vb[e]; }
  }
  const int g5 = tb >> 2, w2 = tb & 3;
#pragma unroll
  for (int m = 0; m < 16; ++m){
    int d0i = th*32 + 2*m, d1i = d0i + 1;
    u32 w0 = (u32)f2bf(fa[2*m])   | ((u32)f2bf(fb[2*m])   << 16);
    u32 w1 = (u32)f2bf(fa[2*m+1]) | ((u32)f2bf(fb[2*m+1]) << 16);
    st[d0i*128 + ((g5 ^ (d0i & 7)) << 2) + w2] = w0;
    st[d1i*128 + ((g5 ^ (d1i & 7)) << 2) + w2] = w1;
  }
  __syncthreads();
  const int rd = t >> 2, rg = t & 3;     // d-row, quarter
  u16* drow = dst + (size_t)(c0 + rd)*32768 + r0;
#pragma unroll
  for (int k = 0; k < 8; ++k){
    int gp = rg + 4*k;
    int slot = gp ^ (rd & 7);
    u32x4 w = *(const u32x4*)(st + rd*128 + slot*4);
    *(u32x4*)(drow + rg*8 + 32*k) = w;
  }
}

static __device__ __forceinline__ void prep_tcvt(int sid, const float* __restrict__ W,
                                                 const float* __restrict__ Wr,
                                                 u16* __restrict__ Wt, u16* __restrict__ Wrt,
                                                 u16* lt){
  const int tix = sid & 7, tiy = (sid >> 3) & 7, tiz = sid >> 6;
  const float* __restrict__ src = tiz ? Wr : W;
  u16* __restrict__ dst = tiz ? Wrt : Wt;
  const int c0 = tix * 64, r0 = tiy * 64;
  const int tid = threadIdx.x;
  const int rr = tid >> 4, c4 = tid & 15;
#pragma unroll
  for (int p = 0; p < 4; ++p){
    int r = rr + p*16;
    f32x4 f = *(const f32x4*)(src + (size_t)(r0 + r)*512 + c0 + c4*4);
#pragma unroll
    for (int e = 0; e < 4; ++e) lt[(c4*4 + e)*72 + r] = f2bf(f[e]);
  }
  __syncthreads();
  const int c = tid >> 2, bg = tid & 3;
  const u32x4* lp = (const u32x4*)(lt + c*72 + bg*16);
  u32x4 w0 = lp[0], w1 = lp[1];
  u16* drow = dst + (size_t)(c0 + c)*512 + r0 + bg*16;
  *(u32x4*)drow = w0;
  *(u32x4*)(drow + 8) = w1;
}

__global__ __launch_bounds__(256) void k_prep(const float* __restrict__ S, const float* __restrict__ P,
                                              const float* __restrict__ W, const float* __restrict__ Wr,
                                              u16* __restrict__ SN, u16* __restrict__ PN,
                                              u16* __restrict__ ST, u16* __restrict__ PT,
                                              u16* __restrict__ Wt, u16* __restrict__ Wrt,
                                              int has_tp){
  __shared__ char sm[32768];
  const int id = blockIdx.x;
  const int nmain = has_tp ? 4096 : 2048;
  if (id < nmain){
    if (has_tp){
      if (id & 1) prep_cvt(id >> 1, S, P, SN, PN);
      else        prep_tp(id >> 1, S, P, ST, PT, (u32*)sm);
    } else {
      prep_cvt(id, S, P, SN, PN);
    }
  } else {
    prep_tcvt(id - nmain, W, Wr, Wt, Wrt, (u16*)sm);
  }
}

// ---------------- bf16 [32768][512] -> [512][32768] transpose (small-ws fallback, post-ln) --
__global__ __launch_bounds__(256) void k_tp(const u16* __restrict__ s0, const u16* __restrict__ s1,
                                            u16* __restrict__ d0, u16* __restrict__ d1){
  const u16* __restrict__ src = blockIdx.z ? s1 : s0;
  u16* __restrict__ dst = blockIdx.z ? d1 : d0;
  __shared__ u32 st[64*128];
  const int r0 = blockIdx.x * 256;   // b tile (fast dim)
  const int c0 = blockIdx.y * 64;    // d tile
  const int t = threadIdx.x;
  const int tb = t & 127, th = t >> 7;     // b-pair, d-half
  const u16* pA = src + (size_t)(r0 + 2*tb)*512 + c0 + th*32;
  u32 a[16], b[16];
  {
    u32x4 a0 = *(const u32x4*)pA,        a1 = *(const u32x4*)(pA + 8);
    u32x4 a2 = *(const u32x4*)(pA + 16), a3 = *(const u32x4*)(pA + 24);
    u32x4 b0 = *(const u32x4*)(pA + 512),  b1 = *(const u32x4*)(pA + 520);
    u32x4 b2 = *(const u32x4*)(pA + 528),  b3 = *(const u32x4*)(pA + 536);
#pragma unroll
    for (int e = 0; e < 4; ++e){
      a[e] = a0[e]; a[4+e] = a1[e]; a[8+e] = a2[e]; a[12+e] = a3[e];
      b[e] = b0[e]; b[4+e] = b1[e]; b[8+e] = b2[e]; b[12+e] = b3[e];
    }
  }
  const int g5 = tb >> 2, w2 = tb & 3;
#pragma unroll
  for (int m = 0; m < 16; ++m){
    u32 lo = a[m], hi = b[m];
    u32 w0 = (lo & 0xFFFFu) | (hi << 16);
    u32 w1 = (lo >> 16) | (hi & 0xFFFF0000u);
    int d0i = th*32 + 2*m, d1i = d0i + 1;
    st[d0i*128 + ((g5 ^ (d0i & 7)) << 2) + w2] = w0;
    st[d1i*128 + ((g5 ^ (d1i & 7)) << 2) + w2] = w1;
  }
  __syncthreads();
  const int rd = t >> 2, rg = t & 3;
  u16* drow = dst + (size_t)(c0 + rd)*32768 + r0;
#pragma unroll
  for (int k = 0; k < 8; ++k){
    int gp = rg + 4*k;
    int slot = gp ^ (rd & 7);
    u32x4 w = *(const u32x4*)(st + rd*128 + slot*4);
    *(u32x4*)(drow + rg*8 + 32*k) = w;
  }
}

// ---------------- forward GEMM (merged S&P): C[m][n] = sum_k A[m][k]*Bt[n][k] ----------------
__global__ __launch_bounds__(512) void k_gemm_fwd(const u16* __restrict__ SN, const u16* __restrict__ PN,
                                                  const u16* __restrict__ Wt, const u16* __restrict__ Wrt,
                                                  u16* __restrict__ SO, u16* __restrict__ RO,
                                                  u16* __restrict__ SOT, u16* __restrict__ ROT){
  __shared__ char smem[67584];
  u16* sA = (u16*)smem;                 // [256 r][8 granules of 8 bf16], swizzle gp^(r&7)
  u16* sB = (u16*)(smem + 32768);       // [128 r][8 granules], swizzle gp^(r&7)
  const int tid = threadIdx.x;
  const int lane = tid & 63, wid = tid >> 6;
  const int wm = wid >> 1, wn = wid & 1;          // 4 x 2 wave grid
  const int l15 = lane & 15, q = lane >> 4;
  const int id = blockIdx.x;
  const int c8 = id & 7, g = id >> 3;             // 128 blocks per XCD
  const int sel = g >> 6, h = g & 63;
  const int yb = c8*16 + (h >> 2), xb = h & 3;
  const int m0 = yb * 256, n0 = xb * 128;
  const u16* __restrict__ A  = sel ? PN  : SN;
  const u16* __restrict__ Bt = sel ? Wrt : Wt;
  u16* __restrict__ Cn = sel ? RO  : SO;
  u16* __restrict__ Ct = sel ? ROT : SOT;

  f32x4 acc[4][4];
  const f32x4 vzero = {0.f, 0.f, 0.f, 0.f};
#pragma unroll
  for (int a = 0; a < 4; ++a)
#pragma unroll
    for (int b = 0; b < 4; ++b) acc[a][b] = vzero;

#pragma unroll 1
  for (int kt = 0; kt < 8; ++kt){
    const int k0 = kt*64;
#pragma unroll
    for (int it = 0; it < 4; ++it){     // A: 256x64 bf16 = 2048 granules
      int gg0 = it*512 + tid;
      int r = gg0 >> 3, gp = gg0 & 7, gsw = gp ^ (r & 7);
      async16(A + (size_t)(m0 + r)*512 + k0 + gsw*8, (char*)sA + (size_t)gg0*16);
    }
#pragma unroll
    for (int it = 0; it < 2; ++it){     // B: 128x64 bf16 = 1024 granules
      int gg0 = it*512 + tid;
      int r = gg0 >> 3, gp = gg0 & 7, gsw = gp ^ (r & 7);
      async16(Bt + (size_t)(n0 + r)*512 + k0 + gsw*8, (char*)sB + (size_t)gg0*16);
    }
    __syncthreads();
#pragma unroll
    for (int kk = 0; kk < 2; ++kk){
      bf16x8 af[4], bfv[4];
#pragma unroll
      for (int mt = 0; mt < 4; ++mt){
        int r = wm*64 + mt*16 + l15;
        int gsw = (kk*4 + q) ^ (r & 7);
        af[mt] = *(const bf16x8*)(sA + (size_t)(r*8 + gsw)*8);
      }
#pragma unroll
      for (int nt = 0; nt < 4; ++nt){
        int r = wn*64 + nt*16 + l15;
        int gsw = (kk*4 + q) ^ (r & 7);
        bfv[nt] = *(const bf16x8*)(sB + (size_t)(r*8 + gsw)*8);
      }
#pragma unroll
      for (int mt = 0; mt < 4; ++mt)
#pragma unroll
        for (int nt = 0; nt < 4; ++nt)
          acc[mt][nt] = __builtin_amdgcn_mfma_f32_16x16x32_bf16(af[mt], bfv[nt], acc[mt][nt], 0, 0, 0);
    }
    __syncthreads();
  }

  // epilogue: natural store + transposed store via LDS round-trip
  u16* lt = (u16*)smem;   // [128 n][264 m] bf16
#pragma unroll
  for (int mt = 0; mt < 4; ++mt)
#pragma unroll
    for (int nt = 0; nt < 4; ++nt){
      f32x4 v = acc[mt][nt];
      u16 b0 = f2bf(v[0]), b1 = f2bf(v[1]), b2 = f2bf(v[2]), b3 = f2bf(v[3]);
      int n = wn*64 + nt*16 + l15;
      int mb = wm*64 + mt*16 + q*4;
      u16* cn = Cn + (size_t)(m0 + mb)*512 + n0 + n;
      cn[0] = b0; cn[512] = b1; cn[1024] = b2; cn[1536] = b3;
      *(u32*)(lt + n*264 + mb)     = (u32)b0 | ((u32)b1 << 16);
      *(u32*)(lt + n*264 + mb + 2) = (u32)b2 | ((u32)b3 << 16);
    }
  __syncthreads();
#pragma unroll
  for (int p = 0; p < 8; ++p){
    int gg0 = p*512 + tid;
    int n = gg0 >> 5, mg = gg0 & 31;
    u32x4 w = *(const u32x4*)(lt + n*264 + mg*8);
    *(u32x4*)(Ct + (size_t)(n0 + n)*32768 + m0 + mg*8) = w;
  }
}

// ---------------- update GEMM: C[i][j] = sum_b At[i][b]*Bt[j][b]; tile 128x256, split-K=32 ---
__global__ __launch_bounds__(512) void k_gemm_upd(const u16* __restrict__ A0, const u16* __restrict__ B0,
                                                  const u16* __restrict__ A1, const u16* __restrict__ B1,
                                                  float* __restrict__ part){
  __shared__ char smem[49152];
  u16* sA = (u16*)smem;                  // [128 r][8 granules], swizzle gp^(r&7)
  u16* sB = (u16*)(smem + 16384);        // [256 r][8 granules], swizzle gp^(r&7)
  const int tid = threadIdx.x;
  const int lane = tid & 63, wid = tid >> 6;
  const int wm = wid >> 2, wn = wid & 3;          // 2 x 4 wave grid (128 m x 256 n)
  const int l15 = lane & 15, q = lane >> 4;
  const int id = blockIdx.x;
  const int c8 = id & 7, g = id >> 3;             // 64 blocks per XCD
  const int zz = c8*8 + (g >> 3);                 // (mat,sp) in [0,64)
  const int xy = g & 7;
  const int mat = zz >> 5, sp = zz & 31;
  const int yb = xy & 3, xb = xy >> 2;
  const u16* __restrict__ A = mat ? A1 : A0;
  const u16* __restrict__ B = mat ? B1 : B0;
  const int m0 = yb * 128, n0 = xb * 256;
  const int kb = sp * 1024;

  f32x4 acc[4][4];
  const f32x4 vzero = {0.f, 0.f, 0.f, 0.f};
#pragma unroll
  for (int a = 0; a < 4; ++a)
#pragma unroll
    for (int b = 0; b < 4; ++b) acc[a][b] = vzero;

#pragma unroll 1
  for (int kt = 0; kt < 16; ++kt){
    const int k0 = kb + kt*64;
#pragma unroll
    for (int it = 0; it < 2; ++it){     // A: 128x64 bf16 = 1024 granules
      int gg0 = it*512 + tid;
      int r = gg0 >> 3, gp = gg0 & 7, gsw = gp ^ (r & 7);
      async16(A + (size_t)(m0 + r)*32768 + k0 + gsw*8, (char*)sA + (size_t)gg0*16);
    }
#pragma unroll
    for (int it = 0; it < 4; ++it){     // B: 256x64 bf16 = 2048 granules
      int gg0 = it*512 + tid;
      int r = gg0 >> 3, gp = gg0 & 7, gsw = gp ^ (r & 7);
      async16(B + (size_t)(n0 + r)*32768 + k0 + gsw*8, (char*)sB + (size_t)gg0*16);
    }
    __syncthreads();
#pragma unroll
    for (int kk = 0; kk < 2; ++kk){
      bf16x8 af[4], bfv[4];
#pragma unroll
      for (int mt = 0; mt < 4; ++mt){
        int r = wm*64 + mt*16 + l15;
        int gsw = (kk*4 + q) ^ (r & 7);
        af[mt] = *(const bf16x8*)(sA + (size_t)(r*8 + gsw)*8);
      }
#pragma unroll
      for (int nt = 0; nt < 4; ++nt){
        int r = wn*64 + nt*16 + l15;
        int gsw = (kk*4 + q) ^ (r & 7);
        bfv[nt] = *(const bf16x8*)(sB + (size_t)(r*8 + gsw)*8);
      }
#pragma unroll
      for (int mt = 0; mt < 4; ++mt)
#pragma unroll
        for (int nt = 0; nt < 4; ++nt)
          acc[mt][nt] = __builtin_amdgcn_mfma_f32_16x16x32_bf16(af[mt], bfv[nt], acc[mt][nt], 0, 0, 0);
    }
    __syncthreads();
  }

  float* dst = part + (size_t)(mat*32 + sp)*262144;
#pragma unroll
  for (int mt = 0; mt < 4; ++mt)
#pragma unroll
    for (int nt = 0; nt < 4; ++nt){
      f32x4 v = acc[mt][nt];
      int n = wn*64 + nt*16 + l15;
      int mb = wm*64 + mt*16 + q*4;
      float* d = dst + (size_t)(m0 + mb)*512 + n0 + n;
      d[0] = v[0]; d[512] = v[1]; d[1024] = v[2]; d[1536] = v[3];
    }
}

// ---------------- fused LN(rec) -> relu(stim+recnorm) -> LN(act): one wave per row ----------
__global__ __launch_bounds__(256) void k_ln(const u16* __restrict__ SO, const u16* __restrict__ RO,
                                            const float* __restrict__ ga, const float* __restrict__ ba,
                                            const float* __restrict__ gr, const float* __restrict__ br,
                                            float* __restrict__ out){
  const int wid = threadIdx.x >> 6, lane = threadIdx.x & 63;
  const size_t b = (size_t)blockIdx.x*4 + wid;
  const int c = lane*8;
  float x[8], t[8];
  {
    u32x4 u = *(const u32x4*)(RO + b*512 + c);
#pragma unroll
    for (int i = 0; i < 4; ++i){
      u32 w = u[i];
      x[2*i]   = __uint_as_float(w << 16);
      x[2*i+1] = __uint_as_float(w & 0xFFFF0000u);
    }
  }
  float s = 0.f, ss = 0.f;
#pragma unroll
  for (int e = 0; e < 8; ++e){ s += x[e]; ss += x[e]*x[e]; }
  s = wave_sum(s); ss = wave_sum(ss);
  float mu = s*(1.f/512.f);
  float var = fmaxf(ss*(1.f/512.f) - mu*mu, 0.f);
  float rs = rsqrtf(var + 1e-5f);
  f32x4 g0 = *(const f32x4*)(gr + c), g1 = *(const f32x4*)(gr + c + 4);
  f32x4 h0 = *(const f32x4*)(br + c), h1 = *(const f32x4*)(br + c + 4);
  {
    u32x4 u = *(const u32x4*)(SO + b*512 + c);
    float so[8];
#pragma unroll
    for (int i = 0; i < 4; ++i){
      u32 w = u[i];
      so[2*i]   = __uint_as_float(w << 16);
      so[2*i+1] = __uint_as_float(w & 0xFFFF0000u);
    }
#pragma unroll
    for (int e = 0; e < 4; ++e) t[e]   = fmaxf(so[e]   + (x[e]  -mu)*rs*g0[e] + h0[e], 0.f);
#pragma unroll
    for (int e = 0; e < 4; ++e) t[4+e] = fmaxf(so[4+e] + (x[4+e]-mu)*rs*g1[e] + h1[e], 0.f);
  }
  float s2 = 0.f, ss2 = 0.f;
#pragma unroll
  for (int e = 0; e < 8; ++e){ s2 += t[e]; ss2 += t[e]*t[e]; }
  s2 = wave_sum(s2); ss2 = wave_sum(ss2);
  float mu2 = s2*(1.f/512.f);
  float var2 = fmaxf(ss2*(1.f/512.f) - mu2*mu2, 0.f);
  float rs2 = rsqrtf(var2 + 1e-5f);
  f32x4 G0 = *(const f32x4*)(ga + c), G1 = *(const f32x4*)(ga + c + 4);
  f32x4 H0 = *(const f32x4*)(ba + c), H1 = *(const f32x4*)(ba + c + 4);
  f32x4 o0, o1;
#pragma unroll
  for (int e = 0; e < 4; ++e){
    o0[e] = (t[e]   - mu2)*rs2*G0[e] + H0[e];
    o1[e] = (t[4+e] - mu2)*rs2*G1[e] + H1[e];
  }
  *(f32x4*)(out + b*512 + c)     = o0;
  *(f32x4*)(out + b*512 + c + 4) = o1;
}

// ---------------- finalize: newW = rownorm(W*(1-decay_i) + alpha_j * heb) ----------------
__global__ __launch_bounds__(256) void k_finalize(const float* __restrict__ W0, const float* __restrict__ W1,
                                                  const float* __restrict__ part,
                                                  const float* __restrict__ alpha, const float* __restrict__ decay,
                                                  float* __restrict__ out){
  const int i = blockIdx.x, mat = blockIdx.y;
  const int t = threadIdx.x;
  const float* Wm = mat ? W1 : W0;
  const float* pb = part + (size_t)mat*32*262144 + (size_t)i*512;
  const float dc = decay[i];
  float v[2], ssq = 0.f;
#pragma unroll
  for (int h = 0; h < 2; ++h){
    int j = t + h*256;
    float acc = 0.f;
#pragma unroll
    for (int sp = 0; sp < 32; ++sp) acc += pb[(size_t)sp*262144 + j];
    float val = Wm[(size_t)i*512 + j]*(1.f - dc) + alpha[j]*acc;
    v[h] = val; ssq += val*val;
  }
  float wsum = wave_sum(ssq);
  __shared__ float red[4];
  const int lane = t & 63, wid = t >> 6;
  if (lane == 0) red[wid] = wsum;
  __syncthreads();
  float tot = red[0] + red[1] + red[2] + red[3];
  float rn = 1.f / fmaxf(sqrtf(tot), 1e-12f);
  out[(size_t)mat*262144 + (size_t)i*512 + t]       = v[0]*rn;
  out[(size_t)mat*262144 + (size_t)i*512 + t + 256] = v[1]*rn;
}

extern "C" void kernel_launch(void* const* d_in, const int* in_sizes, int n_in,
                              void* d_out, int out_size, void* d_ws, size_t ws_size,
                              hipStream_t stream) {
  const float* S  = (const float*)d_in[0];
  const float* P  = (const float*)d_in[1];
  const float* W  = (const float*)d_in[2];
  const float* Wr = (const float*)d_in[3];
  const float* alpha = (const float*)d_in[4];
  const float* decay = (const float*)d_in[5];
  const float* ga = (const float*)d_in[6];
  const float* ba = (const float*)d_in[7];
  const float* gr = (const float*)d_in[8];
  const float* br = (const float*)d_in[9];
  float* out = (float*)d_out;

  char* ws = (char*)d_ws;
  const size_t M32 = 33554432;          // 32 MiB
  const bool big = ws_size >= (size_t)269484032;   // fused plan needs ~257 MiB

  u16 *SN, *PN, *ST, *PT, *SOT, *ROT, *SO, *RO, *Wt, *Wrt;
  if (big){
    SN  = (u16*)(ws);
    PN  = (u16*)(ws + 1*M32);
    ST  = (u16*)(ws + 2*M32);
    PT  = (u16*)(ws + 3*M32);
    SOT = (u16*)(ws + 4*M32);
    ROT = (u16*)(ws + 5*M32);
    SO  = (u16*)(ws + 6*M32);
    RO  = (u16*)(ws + 7*M32);
    Wt  = (u16*)(ws + 8*M32);
    Wrt = (u16*)(ws + 8*M32 + 524288);
  } else {
    // 202.4 MiB plan: ST/PT alias SO/RO (dead after k_ln); part aliases SN/PN
    SN  = (u16*)(ws);
    PN  = (u16*)(ws + 1*M32);
    SOT = (u16*)(ws + 2*M32);
    ROT = (u16*)(ws + 3*M32);
    SO  = (u16*)(ws + 4*M32);
    RO  = (u16*)(ws + 5*M32);
    Wt  = (u16*)(ws + 6*M32);
    Wrt = (u16*)(ws + 6*M32 + 524288);
    ST  = SO;
    PT  = RO;
  }
  float* part = (float*)ws;             // 64 MiB over SN/PN (SN/PN dead before upd)

  // 1) mega prep: cvt grid-stride + (big) fp32->bf16T + W/Wr transposed convert, one dispatch
  k_prep<<<dim3(big ? 4224 : 2176), dim3(256), 0, stream>>>(S, P, W, Wr, SN, PN, ST, PT, Wt, Wrt, big ? 1 : 0);
  // 2) forward GEMMs, merged, 256x128 tiles, XCD-swizzled
  k_gemm_fwd<<<dim3(1024), dim3(512), 0, stream>>>(SN, PN, Wt, Wrt, SO, RO, SOT, ROT);
  // 3) fused double layernorm -> final
  k_ln<<<dim3(8192), dim3(256), 0, stream>>>(SO, RO, ga, ba, gr, br, out);
  // 3b) small-ws fallback: transpose into SO/RO aliases now that they are dead
  if (!big)
    k_tp<<<dim3(128, 8, 2), dim3(256), 0, stream>>>(SN, PN, ST, PT);
  // 4) Hebbian update GEMMs: both operands k-contiguous, 2-barrier loop, split-K=32
  k_gemm_upd<<<dim3(512), dim3(512), 0, stream>>>(ST, SOT, PT, ROT, part);
  // 5) reduce partials + scale + row L2-normalize
  k_finalize<<<dim3(512, 2), dim3(256), 0, stream>>>(W, Wr, part, alpha, decay, out + 16777216);
}

// Round 5
// 325.453 us; speedup vs baseline: 1.1631x; 1.1631x over previous
//
#include <hip/hip_runtime.h>
#include <stdint.h>

typedef unsigned int u32;
typedef unsigned short u16;
typedef float  f32x4 __attribute__((ext_vector_type(4)));
typedef u32    u32x4 __attribute__((ext_vector_type(4)));
typedef __bf16 bf16x8 __attribute__((ext_vector_type(8)));

// fp32 -> bf16 RNE
static __device__ __forceinline__ u16 f2bf(float f){
  u32 u = __builtin_bit_cast(u32, f);
  return (u16)((u + 0x7FFFu + ((u >> 16) & 1u)) >> 16);
}

static __device__ __forceinline__ void async16(const void* g, void* l){
  __builtin_amdgcn_global_load_lds((const __attribute__((address_space(1))) u32*)g,
                                   (__attribute__((address_space(3))) u32*)l, 16, 0, 0);
}

static __device__ __forceinline__ float wave_sum(float v){
#pragma unroll
  for (int o = 32; o > 0; o >>= 1) v += __shfl_xor(v, o, 64);
  return v;
}

// ================= prep: grid-stride cvt (8 iters/thread) + W/Wr transposed convert ========
// Blocks [0,2048): cvt. mat = id>>10, sub = id&1023; 8 independent iterations -> MLP,
// 8x fewer waves than the one-shot R0 k_cvt (tests wave-granularity theory).
// Blocks [2048,2176): tcvt of W/Wr (2 MB total - cannot poison the cvt store stream).
static __device__ __forceinline__ void prep_tcvt(int sid, const float* __restrict__ W,
                                                 const float* __restrict__ Wr,
                                                 u16* __restrict__ Wt, u16* __restrict__ Wrt,
                                                 u16* lt){
  const int tix = sid & 7, tiy = (sid >> 3) & 7, tiz = sid >> 6;
  const float* __restrict__ src = tiz ? Wr : W;
  u16* __restrict__ dst = tiz ? Wrt : Wt;
  const int c0 = tix * 64, r0 = tiy * 64;
  const int tid = threadIdx.x;
  const int rr = tid >> 4, c4 = tid & 15;
#pragma unroll
  for (int p = 0; p < 4; ++p){
    int r = rr + p*16;
    f32x4 f = *(const f32x4*)(src + (size_t)(r0 + r)*512 + c0 + c4*4);
#pragma unroll
    for (int e = 0; e < 4; ++e) lt[(c4*4 + e)*72 + r] = f2bf(f[e]);
  }
  __syncthreads();
  const int c = tid >> 2, bg = tid & 3;
  const u32x4* lp = (const u32x4*)(lt + c*72 + bg*16);
  u32x4 w0 = lp[0], w1 = lp[1];
  u16* drow = dst + (size_t)(c0 + c)*512 + r0 + bg*16;
  *(u32x4*)drow = w0;
  *(u32x4*)(drow + 8) = w1;
}

__global__ __launch_bounds__(256) void k_prep2(const float* __restrict__ S, const float* __restrict__ P,
                                               const float* __restrict__ W, const float* __restrict__ Wr,
                                               u16* __restrict__ SN, u16* __restrict__ PN,
                                               u16* __restrict__ Wt, u16* __restrict__ Wrt){
  __shared__ u16 lt[64*72];
  const int id = blockIdx.x;
  if (id < 2048){
    const int mat = id >> 10, sub = id & 1023;
    const float* __restrict__ src = mat ? P : S;
    u16* __restrict__ dst = mat ? PN : SN;
    const size_t o0 = ((size_t)sub*256 + threadIdx.x) * 8;   // iter stride 1024*256*8 = 2097152
#pragma unroll
    for (int j = 0; j < 8; ++j){
      size_t o = o0 + (size_t)j*2097152;
      f32x4 a = *(const f32x4*)(src + o);
      f32x4 b = *(const f32x4*)(src + o + 4);
      u32x4 w;
      w[0] = (u32)f2bf(a[0]) | ((u32)f2bf(a[1]) << 16);
      w[1] = (u32)f2bf(a[2]) | ((u32)f2bf(a[3]) << 16);
      w[2] = (u32)f2bf(b[0]) | ((u32)f2bf(b[1]) << 16);
      w[3] = (u32)f2bf(b[2]) | ((u32)f2bf(b[3]) << 16);
      *(u32x4*)(dst + o) = w;
    }
  } else {
    prep_tcvt(id - 2048, W, Wr, Wt, Wrt, lt);
  }
}

// ---------------- forward GEMM (merged S&P): C[m][n] = sum_k A[m][k]*Bt[n][k] ----------------
// Tile 256x128, BK=64, 512 threads. A bf16 natural; dual-store Cn + Ct.
__global__ __launch_bounds__(512) void k_gemm_fwd(const u16* __restrict__ SN, const u16* __restrict__ PN,
                                                  const u16* __restrict__ Wt, const u16* __restrict__ Wrt,
                                                  u16* __restrict__ SO, u16* __restrict__ RO,
                                                  u16* __restrict__ SOT, u16* __restrict__ ROT){
  __shared__ char smem[67584];
  u16* sA = (u16*)smem;                 // [256 r][8 granules of 8 bf16], swizzle gp^(r&7)
  u16* sB = (u16*)(smem + 32768);       // [128 r][8 granules], swizzle gp^(r&7)
  const int tid = threadIdx.x;
  const int lane = tid & 63, wid = tid >> 6;
  const int wm = wid >> 1, wn = wid & 1;          // 4 x 2 wave grid
  const int l15 = lane & 15, q = lane >> 4;
  const int id = blockIdx.x;
  const int c8 = id & 7, g = id >> 3;             // 128 blocks per XCD
  const int sel = g >> 6, h = g & 63;
  const int yb = c8*16 + (h >> 2), xb = h & 3;
  const int m0 = yb * 256, n0 = xb * 128;
  const u16* __restrict__ A  = sel ? PN  : SN;
  const u16* __restrict__ Bt = sel ? Wrt : Wt;
  u16* __restrict__ Cn = sel ? RO  : SO;
  u16* __restrict__ Ct = sel ? ROT : SOT;

  f32x4 acc[4][4];
  const f32x4 vzero = {0.f, 0.f, 0.f, 0.f};
#pragma unroll
  for (int a = 0; a < 4; ++a)
#pragma unroll
    for (int b = 0; b < 4; ++b) acc[a][b] = vzero;

#pragma unroll 1
  for (int kt = 0; kt < 8; ++kt){
    const int k0 = kt*64;
#pragma unroll
    for (int it = 0; it < 4; ++it){     // A: 256x64 bf16 = 2048 granules
      int gg0 = it*512 + tid;
      int r = gg0 >> 3, gp = gg0 & 7, gsw = gp ^ (r & 7);
      async16(A + (size_t)(m0 + r)*512 + k0 + gsw*8, (char*)sA + (size_t)gg0*16);
    }
#pragma unroll
    for (int it = 0; it < 2; ++it){     // B: 128x64 bf16 = 1024 granules
      int gg0 = it*512 + tid;
      int r = gg0 >> 3, gp = gg0 & 7, gsw = gp ^ (r & 7);
      async16(Bt + (size_t)(n0 + r)*512 + k0 + gsw*8, (char*)sB + (size_t)gg0*16);
    }
    __syncthreads();
#pragma unroll
    for (int kk = 0; kk < 2; ++kk){
      bf16x8 af[4], bfv[4];
#pragma unroll
      for (int mt = 0; mt < 4; ++mt){
        int r = wm*64 + mt*16 + l15;
        int gsw = (kk*4 + q) ^ (r & 7);
        af[mt] = *(const bf16x8*)(sA + (size_t)(r*8 + gsw)*8);
      }
#pragma unroll
      for (int nt = 0; nt < 4; ++nt){
        int r = wn*64 + nt*16 + l15;
        int gsw = (kk*4 + q) ^ (r & 7);
        bfv[nt] = *(const bf16x8*)(sB + (size_t)(r*8 + gsw)*8);
      }
#pragma unroll
      for (int mt = 0; mt < 4; ++mt)
#pragma unroll
        for (int nt = 0; nt < 4; ++nt)
          acc[mt][nt] = __builtin_amdgcn_mfma_f32_16x16x32_bf16(af[mt], bfv[nt], acc[mt][nt], 0, 0, 0);
    }
    __syncthreads();
  }

  // epilogue: natural store + transposed store via LDS round-trip
  u16* lt = (u16*)smem;   // [128 n][264 m] bf16
#pragma unroll
  for (int mt = 0; mt < 4; ++mt)
#pragma unroll
    for (int nt = 0; nt < 4; ++nt){
      f32x4 v = acc[mt][nt];
      u16 b0 = f2bf(v[0]), b1 = f2bf(v[1]), b2 = f2bf(v[2]), b3 = f2bf(v[3]);
      int n = wn*64 + nt*16 + l15;
      int mb = wm*64 + mt*16 + q*4;
      u16* cn = Cn + (size_t)(m0 + mb)*512 + n0 + n;
      cn[0] = b0; cn[512] = b1; cn[1024] = b2; cn[1536] = b3;
      *(u32*)(lt + n*264 + mb)     = (u32)b0 | ((u32)b1 << 16);
      *(u32*)(lt + n*264 + mb + 2) = (u32)b2 | ((u32)b3 << 16);
    }
  __syncthreads();
#pragma unroll
  for (int p = 0; p < 8; ++p){
    int gg0 = p*512 + tid;
    int n = gg0 >> 5, mg = gg0 & 31;
    u32x4 w = *(const u32x4*)(lt + n*264 + mg*8);
    *(u32x4*)(Ct + (size_t)(n0 + n)*32768 + m0 + mg*8) = w;
  }
}

// ---------------- update GEMM (R0-proven): C[i][j] = sum_b A[b][i]*B[j][b]; split-K=32 -------
// A natural bf16 (SN/PN) with in-LDS transpose; B transposed (SOT/ROT).
// LDS map: sAn [0,16384) = 64k x 128i bf16; sAt [16384,34816) = 128i x 36 u32;
//          sB [34816,67584) = 256j x 64k bf16.
__global__ __launch_bounds__(512) void k_gemm_upd(const u16* __restrict__ A0, const u16* __restrict__ B0,
                                                  const u16* __restrict__ A1, const u16* __restrict__ B1,
                                                  float* __restrict__ part){
  __shared__ char smem[67584];
  char* sAn = smem;
  u32*  sAt = (u32*)(smem + 16384);
  u16*  sB  = (u16*)(smem + 34816);
  const int tid = threadIdx.x;
  const int lane = tid & 63, wid = tid >> 6;
  const int wm = wid >> 2, wn = wid & 3;          // 2 x 4 wave grid (128 m x 256 n)
  const int l15 = lane & 15, q = lane >> 4;
  const int id = blockIdx.x;
  const int c8 = id & 7, g = id >> 3;             // 64 blocks per XCD
  const int zz = c8*8 + (g >> 3);                 // (mat,sp) in [0,64)
  const int xy = g & 7;
  const int mat = zz >> 5, sp = zz & 31;
  const int yb = xy & 3, xb = xy >> 2;
  const u16* __restrict__ A = mat ? A1 : A0;
  const u16* __restrict__ B = mat ? B1 : B0;
  const int m0 = yb * 128, n0 = xb * 256;
  const int kb = sp * 1024;
  // transpose assignment: lane-local chunk/pair
  const int base_c = tid >> 5, pr = tid & 31;
  const int ce = (base_c + pr) & 15;

  f32x4 acc[4][4];
  const f32x4 vzero = {0.f, 0.f, 0.f, 0.f};
#pragma unroll
  for (int a = 0; a < 4; ++a)
#pragma unroll
    for (int b = 0; b < 4; ++b) acc[a][b] = vzero;

#pragma unroll 1
  for (int kt = 0; kt < 16; ++kt){
    const int k0 = kb + kt*64;
#pragma unroll
    for (int it = 0; it < 2; ++it){     // A natural: 64 rows x 128 cols bf16 = 1024 granules
      int gg0 = it*512 + tid;
      int r = gg0 >> 4, gp = gg0 & 15;  // 16 granules per 128-col row, plain layout
      async16(A + (size_t)(k0 + r)*512 + m0 + gp*8, sAn + (size_t)gg0*16);
    }
#pragma unroll
    for (int it = 0; it < 4; ++it){     // B: 256 rows x 64 k bf16 = 2048 granules
      int gg0 = it*512 + tid;
      int r = gg0 >> 3, gp = gg0 & 7, gsw = gp ^ (r & 7);
      async16(B + (size_t)(n0 + r)*32768 + k0 + gsw*8, (char*)sB + (size_t)gg0*16);
    }
    __syncthreads();
    // in-LDS transpose of A: [64 k][128 i] -> sAt[i][pr] (k-pairs packed in u32)
    {
      u32x4 r0 = *(const u32x4*)(sAn + (size_t)(2*pr)*256 + ce*16);
      u32x4 r1 = *(const u32x4*)(sAn + (size_t)(2*pr)*256 + 256 + ce*16);
#pragma unroll
      for (int e = 0; e < 4; ++e){
        u32 lo = r0[e], hi = r1[e];
        sAt[(ce*8 + 2*e    )*36 + pr] = (lo & 0xFFFFu) | (hi << 16);
        sAt[(ce*8 + 2*e + 1)*36 + pr] = (lo >> 16) | (hi & 0xFFFF0000u);
      }
    }
    __syncthreads();
#pragma unroll
    for (int kk = 0; kk < 2; ++kk){
      bf16x8 af[4], bfv[4];
#pragma unroll
      for (int mt = 0; mt < 4; ++mt){
        int r = wm*64 + mt*16 + l15;
        af[mt] = *(const bf16x8*)(sAt + (size_t)r*36 + kk*16 + q*4);
      }
#pragma unroll
      for (int nt = 0; nt < 4; ++nt){
        int r = wn*64 + nt*16 + l15;
        int gsw = (kk*4 + q) ^ (r & 7);
        bfv[nt] = *(const bf16x8*)(sB + (size_t)(r*8 + gsw)*8);
      }
#pragma unroll
      for (int mt = 0; mt < 4; ++mt)
#pragma unroll
        for (int nt = 0; nt < 4; ++nt)
          acc[mt][nt] = __builtin_amdgcn_mfma_f32_16x16x32_bf16(af[mt], bfv[nt], acc[mt][nt], 0, 0, 0);
    }
    __syncthreads();
  }

  float* dst = part + (size_t)(mat*32 + sp)*262144;
#pragma unroll
  for (int mt = 0; mt < 4; ++mt)
#pragma unroll
    for (int nt = 0; nt < 4; ++nt){
      f32x4 v = acc[mt][nt];
      int n = wn*64 + nt*16 + l15;
      int mb = wm*64 + mt*16 + q*4;
      float* d = dst + (size_t)(m0 + mb)*512 + n0 + n;
      d[0] = v[0]; d[512] = v[1]; d[1024] = v[2]; d[1536] = v[3];
    }
}

// ---------------- fused LN(rec) -> relu(stim+recnorm) -> LN(act): one wave per row ----------
__global__ __launch_bounds__(256) void k_ln(const u16* __restrict__ SO, const u16* __restrict__ RO,
                                            const float* __restrict__ ga, const float* __restrict__ ba,
                                            const float* __restrict__ gr, const float* __restrict__ br,
                                            float* __restrict__ out){
  const int wid = threadIdx.x >> 6, lane = threadIdx.x & 63;
  const size_t b = (size_t)blockIdx.x*4 + wid;
  const int c = lane*8;
  float x[8], t[8];
  {
    u32x4 u = *(const u32x4*)(RO + b*512 + c);
#pragma unroll
    for (int i = 0; i < 4; ++i){
      u32 w = u[i];
      x[2*i]   = __uint_as_float(w << 16);
      x[2*i+1] = __uint_as_float(w & 0xFFFF0000u);
    }
  }
  float s = 0.f, ss = 0.f;
#pragma unroll
  for (int e = 0; e < 8; ++e){ s += x[e]; ss += x[e]*x[e]; }
  s = wave_sum(s); ss = wave_sum(ss);
  float mu = s*(1.f/512.f);
  float var = fmaxf(ss*(1.f/512.f) - mu*mu, 0.f);
  float rs = rsqrtf(var + 1e-5f);
  f32x4 g0 = *(const f32x4*)(gr + c), g1 = *(const f32x4*)(gr + c + 4);
  f32x4 h0 = *(const f32x4*)(br + c), h1 = *(const f32x4*)(br + c + 4);
  {
    u32x4 u = *(const u32x4*)(SO + b*512 + c);
    float so[8];
#pragma unroll
    for (int i = 0; i < 4; ++i){
      u32 w = u[i];
      so[2*i]   = __uint_as_float(w << 16);
      so[2*i+1] = __uint_as_float(w & 0xFFFF0000u);
    }
#pragma unroll
    for (int e = 0; e < 4; ++e) t[e]   = fmaxf(so[e]   + (x[e]  -mu)*rs*g0[e] + h0[e], 0.f);
#pragma unroll
    for (int e = 0; e < 4; ++e) t[4+e] = fmaxf(so[4+e] + (x[4+e]-mu)*rs*g1[e] + h1[e], 0.f);
  }
  float s2 = 0.f, ss2 = 0.f;
#pragma unroll
  for (int e = 0; e < 8; ++e){ s2 += t[e]; ss2 += t[e]*t[e]; }
  s2 = wave_sum(s2); ss2 = wave_sum(ss2);
  float mu2 = s2*(1.f/512.f);
  float var2 = fmaxf(ss2*(1.f/512.f) - mu2*mu2, 0.f);
  float rs2 = rsqrtf(var2 + 1e-5f);
  f32x4 G0 = *(const f32x4*)(ga + c), G1 = *(const f32x4*)(ga + c + 4);
  f32x4 H0 = *(const f32x4*)(ba + c), H1 = *(const f32x4*)(ba + c + 4);
  f32x4 o0, o1;
#pragma unroll
  for (int e = 0; e < 4; ++e){
    o0[e] = (t[e]   - mu2)*rs2*G0[e] + H0[e];
    o1[e] = (t[4+e] - mu2)*rs2*G1[e] + H1[e];
  }
  *(f32x4*)(out + b*512 + c)     = o0;
  *(f32x4*)(out + b*512 + c + 4) = o1;
}

// ---------------- finalize: newW = rownorm(W*(1-decay_i) + alpha_j * heb) ----------------
__global__ __launch_bounds__(256) void k_finalize(const float* __restrict__ W0, const float* __restrict__ W1,
                                                  const float* __restrict__ part,
                                                  const float* __restrict__ alpha, const float* __restrict__ decay,
                                                  float* __restrict__ out){
  const int i = blockIdx.x, mat = blockIdx.y;
  const int t = threadIdx.x;
  const float* Wm = mat ? W1 : W0;
  const float* pb = part + (size_t)mat*32*262144 + (size_t)i*512;
  const float dc = decay[i];
  float v[2], ssq = 0.f;
#pragma unroll
  for (int h = 0; h < 2; ++h){
    int j = t + h*256;
    float acc = 0.f;
#pragma unroll
    for (int sp = 0; sp < 32; ++sp) acc += pb[(size_t)sp*262144 + j];
    float val = Wm[(size_t)i*512 + j]*(1.f - dc) + alpha[j]*acc;
    v[h] = val; ssq += val*val;
  }
  float wsum = wave_sum(ssq);
  __shared__ float red[4];
  const int lane = t & 63, wid = t >> 6;
  if (lane == 0) red[wid] = wsum;
  __syncthreads();
  float tot = red[0] + red[1] + red[2] + red[3];
  float rn = 1.f / fmaxf(sqrtf(tot), 1e-12f);
  out[(size_t)mat*262144 + (size_t)i*512 + t]       = v[0]*rn;
  out[(size_t)mat*262144 + (size_t)i*512 + t + 256] = v[1]*rn;
}

extern "C" void kernel_launch(void* const* d_in, const int* in_sizes, int n_in,
                              void* d_out, int out_size, void* d_ws, size_t ws_size,
                              hipStream_t stream) {
  const float* S  = (const float*)d_in[0];
  const float* P  = (const float*)d_in[1];
  const float* W  = (const float*)d_in[2];
  const float* Wr = (const float*)d_in[3];
  const float* alpha = (const float*)d_in[4];
  const float* decay = (const float*)d_in[5];
  const float* ga = (const float*)d_in[6];
  const float* ba = (const float*)d_in[7];
  const float* gr = (const float*)d_in[8];
  const float* br = (const float*)d_in[9];
  float* out = (float*)d_out;

  char* ws = (char*)d_ws;
  u16* SN  = (u16*)(ws);                    // [32768][512] S bf16 natural   32 MiB
  u16* PN  = (u16*)(ws + 33554432);         // [32768][512] P bf16 natural
  u16* SOT = (u16*)(ws + 67108864);         // [512][32768] (S@W)^T
  u16* ROT = (u16*)(ws + 100663296);        // [512][32768] (P@Wr)^T
  u16* SO  = (u16*)(ws + 134217728);        // [32768][512] S@W
  u16* RO  = (u16*)(ws + 167772160);        // [32768][512] P@Wr
  u16* Wt  = (u16*)(ws + 201326592);        // [512][512] W^T bf16
  u16* Wrt = (u16*)(ws + 201850880);        // [512][512] Wr^T bf16
  // split-K=32 partials alias SO/RO (dead after k_ln): 2*32*512*512*4 = 64 MiB exact
  float* part = (float*)(ws + 134217728);

  // 1) converts: grid-stride cvt + W/Wr transposed convert in one dispatch
  k_prep2<<<dim3(2176), dim3(256), 0, stream>>>(S, P, W, Wr, SN, PN, Wt, Wrt);
  // 2) forward GEMMs, merged, 256x128 tiles, XCD-swizzled
  k_gemm_fwd<<<dim3(1024), dim3(512), 0, stream>>>(SN, PN, Wt, Wrt, SO, RO, SOT, ROT);
  // 3) fused double layernorm -> final
  k_ln<<<dim3(8192), dim3(256), 0, stream>>>(SO, RO, ga, ba, gr, br, out);
  // 4) Hebbian update GEMMs, 128x256 tiles, in-LDS A-transpose, split-K=32
  k_gemm_upd<<<dim3(512), dim3(512), 0, stream>>>(SN, SOT, PN, ROT, part);
  // 5) reduce partials + scale + row L2-normalize
  k_finalize<<<dim3(512, 2), dim3(256), 0, stream>>>(W, Wr, part, alpha, decay, out + 16777216);
}